// Round 5
// baseline (2141.161 us; speedup 1.0000x reference)
//
#include <hip/hip_runtime.h>

#define N_NODES 2048
#define C_CH    128
#define N_SPEC  10

#define NT2 45     // multisets (a<=b) of 9
#define NT3 165    // multisets (a<=b<=j) of 9

typedef _Float16 half8 __attribute__((ext_vector_type(8)));

// ---- compile-time row indices for the symmetric enumerations ----
__host__ __device__ constexpr int t2idx(int a, int b) {
    int s = 0; for (int x = 0; x < a; ++x) s += 9 - x;
    return s + (b - a);
}
__host__ __device__ constexpr int t3idx(int a, int b, int j) {
    int s = 0;
    for (int x = 0; x < a; ++x) s += (9 - x) * (10 - x) / 2;
    for (int y = a; y < b; ++y) s += 9 - y;
    return s + (j - b);
}

// ---- ws layout ----
// ints:   counts @0 (16), lists @16 (10*2048)
// floats: Up region @ float offset 32768
#define WS_UP_OFF 32768
#define UA3_OFF 0       // 165*10        = 1650 floats
#define UB3_OFF 1664    // 165*3*11      = 5445
#define UC3_OFF 7168    // 165*5*13      = 10725
#define U2A_OFF 17920   // 45*3          = 135
#define U2B_OFF 18064   // 45*3*2        = 270
#define U2C_OFF 18336   // 45*5*3        = 675
#define PRESYM_TOTAL 18900

// ---------------------------------------------------------------------------
// Kernel 1: bucket nodes by species (parallel; counts pre-zeroed by memset).
// ---------------------------------------------------------------------------
__global__ __launch_bounds__(256) void bucket_kernel(const int* __restrict__ index,
                                                     int* __restrict__ counts,
                                                     int* __restrict__ lists) {
    int n = blockIdx.x * 256 + threadIdx.x;
    if (n < N_NODES) {
        int s = index[n];
        int pos = atomicAdd(&counts[s], 1);
        lists[s * N_NODES + pos] = n;
    }
}

// ---------------------------------------------------------------------------
// Kernel 2: presymmetrize U3 over (a,b,j), U2 over (a,b). c,s-independent.
// ---------------------------------------------------------------------------
__device__ __forceinline__ void decode3(int t, int& a, int& b, int& j) {
    int aa = 0;
    for (; aa < 9; ++aa) { int n = (9 - aa) * (10 - aa) / 2; if (t < n) break; t -= n; }
    a = aa;
    int bb = aa;
    for (; bb < 9; ++bb) { int n = 9 - bb; if (t < n) break; t -= n; }
    b = bb; j = bb + t;
}
__device__ __forceinline__ void decode2(int t, int& a, int& b) {
    int aa = 0;
    for (; aa < 9; ++aa) { int n = 9 - aa; if (t < n) break; t -= n; }
    a = aa; b = aa + t;
}

template<int M, int R>
__device__ __forceinline__ float symsum3(const float* __restrict__ u, int a, int b, int j, int k, int il) {
#define RD(p,q,r) u[((((p)*9+(q))*9+(r))*M + k)*R + il]
    float v;
    if (a == b && b == j) v = RD(a,a,a);
    else if (a == b)      v = RD(a,a,j) + RD(a,j,a) + RD(j,a,a);
    else if (b == j)      v = RD(a,b,b) + RD(b,a,b) + RD(b,b,a);
    else v = RD(a,b,j) + RD(a,j,b) + RD(b,a,j) + RD(b,j,a) + RD(j,a,b) + RD(j,b,a);
#undef RD
    return v;
}
template<int M, int R>
__device__ __forceinline__ float symsum2(const float* __restrict__ u, int a, int b, int k, int il) {
#define RD(p,q) u[(((p)*9+(q))*M + k)*R + il]
    float v = (a == b) ? RD(a,a) : (RD(a,b) + RD(b,a));
#undef RD
    return v;
}

__global__ __launch_bounds__(256) void presym_kernel(const float* __restrict__ u30,
                                                     const float* __restrict__ u31,
                                                     const float* __restrict__ u32,
                                                     const float* __restrict__ u20,
                                                     const float* __restrict__ u21,
                                                     const float* __restrict__ u22,
                                                     float* __restrict__ Up) {
    int g = blockIdx.x * 256 + threadIdx.x;
    if (g < 1650) {
        int t = g / 10, k = g - t * 10; int a, b, j; decode3(t, a, b, j);
        Up[UA3_OFF + g] = symsum3<10, 1>(u30, a, b, j, k, 0);
    } else if (g < 7095) {
        int e = g - 1650; int k = e % 11, r = e / 11, il = r % 3, t = r / 3;
        int a, b, j; decode3(t, a, b, j);
        Up[UB3_OFF + e] = symsum3<11, 3>(u31, a, b, j, k, il);
    } else if (g < 17820) {
        int e = g - 7095; int k = e % 13, r = e / 13, il = r % 5, t = r / 5;
        int a, b, j; decode3(t, a, b, j);
        Up[UC3_OFF + e] = symsum3<13, 5>(u32, a, b, j, k, il);
    } else if (g < 17955) {
        int e = g - 17820; int k = e % 3, t = e / 3; int a, b; decode2(t, a, b);
        Up[U2A_OFF + e] = symsum2<3, 1>(u20, a, b, k, 0);
    } else if (g < 18225) {
        int e = g - 17955; int k = e % 2, r = e / 2, il = r % 3, t = r / 3;
        int a, b; decode2(t, a, b);
        Up[U2B_OFF + e] = symsum2<2, 3>(u21, a, b, k, il);
    } else if (g < PRESYM_TOTAL) {
        int e = g - 18225; int k = e % 3, r = e / 3, il = r % 5, t = r / 5;
        int a, b; decode2(t, a, b);
        Up[U2C_OFF + e] = symsum2<3, 5>(u22, a, b, k, il);
    }
}

// ---------------------------------------------------------------------------
struct Params {
    const float* W3[3];   // W3_{0e,1o,2e}
    const float* W2[3];   // W2_{0e,1o,2e}
    const float* U1[3];   // U1_{0e,1o,2e}
    const float* W1[3];   // W1_{0e,1o,2e}
};

template <int M>
__device__ __forceinline__ float dotk(const float* __restrict__ up, const float* __restrict__ wp) {
    float acc = 0.f;
#pragma unroll
    for (int k = 0; k < M; ++k) acc = __builtin_fmaf(up[k], wp[k * C_CH], acc);
    return acc;
}

// one coefficient row (9 fp16 coefs) applied to 2 nodes with weights m0, m1
__device__ __forceinline__ void frow(const half8 hv, const _Float16 e8, float m0, float m1,
                                     float* __restrict__ o0, float* __restrict__ o1) {
#pragma unroll
    for (int i = 0; i < 8; ++i) {
        float cc = (float)hv[i];
        o0[i] = __builtin_fmaf(cc, m0, o0[i]);
        o1[i] = __builtin_fmaf(cc, m1, o1[i]);
    }
    float c8 = (float)e8;
    o0[8] = __builtin_fmaf(c8, m0, o0[8]);
    o1[8] = __builtin_fmaf(c8, m1, o1[8]);
}

// ---------------------------------------------------------------------------
// Kernel 3: fused build + eval. 1 wave per (s, c, half). 219 fp16 rows in LDS,
// 2 nodes/thread, all monomial indices compile-time (full symmetrization).
// launch_bounds(64,1): VGPR cap 512 so the allocator never spills; the grid
// (10 waves/CU) is the occupancy limiter anyway.
// ---------------------------------------------------------------------------
__global__ __launch_bounds__(64, 1) void eval_kernel(const float* __restrict__ nf,
                                                     const int* __restrict__ counts,
                                                     const int* __restrict__ lists,
                                                     const float* __restrict__ Up,
                                                     Params p,
                                                     float* __restrict__ out) {
    __shared__ __align__(16) _Float16 sC3[NT3 * 8];
    __shared__ __align__(4)  _Float16 sC3b[NT3 + 1];
    __shared__ __align__(16) _Float16 sC2[NT2 * 8];
    __shared__ __align__(4)  _Float16 sC2b[NT2 + 1];
    __shared__ __align__(16) _Float16 sC1[9 * 8];
    __shared__ __align__(4)  _Float16 sC1b[10];

    const int bi = blockIdx.x;
    const int s = bi % N_SPEC;
    const int c = (bi / N_SPEC) % C_CH;
    const int h = bi / (N_SPEC * C_CH);
    const int tid = threadIdx.x;

    // ---- build C3 (165 rows, fp16) ----
    {
        const float* UA = Up + UA3_OFF;
        const float* UB = Up + UB3_OFF;
        const float* UC = Up + UC3_OFF;
        const float* w30 = p.W3[0] + (s * 10) * C_CH + c;
        const float* w31 = p.W3[1] + (s * 11) * C_CH + c;
        const float* w32 = p.W3[2] + (s * 13) * C_CH + c;
        for (int e = tid; e < NT3 * 9; e += 64) {
            int t = e / 9, i = e - t * 9;
            float v;
            if (i == 0)     v = dotk<10>(UA + t * 10, w30);
            else if (i < 4) v = dotk<11>(UB + (t * 3 + (i - 1)) * 11, w31);
            else            v = dotk<13>(UC + (t * 5 + (i - 4)) * 13, w32);
            if (i < 8) sC3[t * 8 + i] = (_Float16)v; else sC3b[t] = (_Float16)v;
        }
    }
    // ---- build C2 (45 rows, fp16) ----
    {
        const float* VA = Up + U2A_OFF;
        const float* VB = Up + U2B_OFF;
        const float* VC = Up + U2C_OFF;
        const float* w20 = p.W2[0] + (s * 3) * C_CH + c;
        const float* w21 = p.W2[1] + (s * 2) * C_CH + c;
        const float* w22 = p.W2[2] + (s * 3) * C_CH + c;
        for (int e = tid; e < NT2 * 9; e += 64) {
            int t = e / 9, i = e - t * 9;
            float v;
            if (i == 0)     v = dotk<3>(VA + t * 3, w20);
            else if (i < 4) v = dotk<2>(VB + (t * 3 + (i - 1)) * 2, w21);
            else            v = dotk<3>(VC + (t * 5 + (i - 4)) * 3, w22);
            if (i < 8) sC2[t * 8 + i] = (_Float16)v; else sC2b[t] = (_Float16)v;
        }
    }
    // ---- build C1 (9 rows, fp16); mul=1 so the dot is a single product ----
    {
        const float w10 = p.W1[0][s * C_CH + c];
        const float w11 = p.W1[1][s * C_CH + c];
        const float w12 = p.W1[2][s * C_CH + c];
        for (int e = tid; e < 81; e += 64) {
            int a = e / 9, i = e - a * 9;
            float v;
            if (i == 0)     v = p.U1[0][a] * w10;
            else if (i < 4) v = p.U1[1][a * 3 + (i - 1)] * w11;
            else            v = p.U1[2][a * 5 + (i - 4)] * w12;
            if (i < 8) sC1[a * 8 + i] = (_Float16)v; else sC1b[a] = (_Float16)v;
        }
    }
    __syncthreads();

    const int cnt = counts[s];
    const half8* C3v = (const half8*)sC3;
    const half8* C2v = (const half8*)sC2;
    const half8* C1v = (const half8*)sC1;

    for (int base = h * 128; base < cnt; base += 256) {
        int i0 = base + tid;
        int i1 = base + 64 + tid;
        const int n0 = (i0 < cnt) ? lists[s * N_NODES + i0] : -1;
        const int n1 = (i1 < cnt) ? lists[s * N_NODES + i1] : -1;

        const float* x0p = nf + ((long)(n0 < 0 ? 0 : n0) * C_CH + c) * 9;
        const float* x1p = nf + ((long)(n1 < 0 ? 0 : n1) * C_CH + c) * 9;
        float x0[9], x1[9];
#pragma unroll
        for (int j = 0; j < 9; ++j) { x0[j] = x0p[j]; x1[j] = x1p[j]; }

        float o0[9], o1[9];
#pragma unroll
        for (int i = 0; i < 9; ++i) { o0[i] = 0.f; o1[i] = 0.f; }

#pragma unroll
        for (int a = 0; a < 9; ++a) {
            frow(C1v[a], sC1b[a], x0[a], x1[a], o0, o1);
#pragma unroll
            for (int b = a; b < 9; ++b) {
                const float p0 = x0[a] * x0[b];
                const float p1 = x1[a] * x1[b];
                frow(C2v[t2idx(a, b)], sC2b[t2idx(a, b)], p0, p1, o0, o1);
#pragma unroll
                for (int j = b; j < 9; ++j) {
                    frow(C3v[t3idx(a, b, j)], sC3b[t3idx(a, b, j)],
                         p0 * x0[j], p1 * x1[j], o0, o1);
                }
            }
        }

        if (n0 >= 0) {
            float* op = out + ((long)n0 * C_CH + c) * 9;
#pragma unroll
            for (int i = 0; i < 9; ++i) op[i] = o0[i];
        }
        if (n1 >= 0) {
            float* op = out + ((long)n1 * C_CH + c) * 9;
#pragma unroll
            for (int i = 0; i < 9; ++i) op[i] = o1[i];
        }
    }
}

// ---------------------------------------------------------------------------
extern "C" void kernel_launch(void* const* d_in, const int* in_sizes, int n_in,
                              void* d_out, int out_size, void* d_ws, size_t ws_size,
                              hipStream_t stream) {
    const float* nf  = (const float*)d_in[0];
    const int* index = (const int*)d_in[1];

    Params p;
    p.W3[0] = (const float*)d_in[3];
    p.W3[1] = (const float*)d_in[5];
    p.W3[2] = (const float*)d_in[7];
    p.W2[0] = (const float*)d_in[9];
    p.W2[1] = (const float*)d_in[11];
    p.W2[2] = (const float*)d_in[13];
    p.U1[0] = (const float*)d_in[14];
    p.U1[1] = (const float*)d_in[16];
    p.U1[2] = (const float*)d_in[18];
    p.W1[0] = (const float*)d_in[15];
    p.W1[1] = (const float*)d_in[17];
    p.W1[2] = (const float*)d_in[19];

    int* counts = (int*)d_ws;
    int* lists  = (int*)d_ws + 16;
    float* Up   = (float*)d_ws + WS_UP_OFF;

    hipMemsetAsync(counts, 0, 16 * sizeof(int), stream);
    bucket_kernel<<<(N_NODES + 255) / 256, 256, 0, stream>>>(index, counts, lists);
    presym_kernel<<<(PRESYM_TOTAL + 255) / 256, 256, 0, stream>>>(
        (const float*)d_in[2], (const float*)d_in[4], (const float*)d_in[6],
        (const float*)d_in[8], (const float*)d_in[10], (const float*)d_in[12], Up);
    eval_kernel<<<N_SPEC * C_CH * 2, 64, 0, stream>>>(nf, counts, lists, Up, p, (float*)d_out);
}

// Round 6
// 708.713 us; speedup vs baseline: 3.0212x; 3.0212x over previous
//
#include <hip/hip_runtime.h>

#define N_NODES 2048
#define C_CH    128
#define N_SPEC  10

#define NTRI  45            // (b<=j) pairs
#define NROW3 (9 * NTRI)    // 405 partially-symmetrized cubic rows

// ws layout: counts @0 (16 ints), lists @16 (10*2048 ints), Up @ float ofs 32768
#define WS_UP_OFF 32768
#define UPA_SZ 4096        // 9*45*1*10 = 4050, padded
#define UPB_SZ 13376       // 9*45*3*11 = 13365, padded
// UPC: 9*45*5*13 = 26325

#if __has_builtin(__builtin_amdgcn_sched_barrier)
#define SCHED_FENCE() __builtin_amdgcn_sched_barrier(0)
#else
#define SCHED_FENCE()
#endif

// triangle index for b<=j (compile-time in unrolled loops)
__host__ __device__ constexpr int t2idx(int b, int j) {
    int s = 0; for (int x = 0; x < b; ++x) s += 9 - x;
    return s + (j - b);
}

// ---------------------------------------------------------------------------
// Kernel 1: bucket nodes by species (counts pre-zeroed by async memset).
// ---------------------------------------------------------------------------
__global__ __launch_bounds__(256) void bucket_kernel(const int* __restrict__ index,
                                                     int* __restrict__ counts,
                                                     int* __restrict__ lists) {
    int n = blockIdx.x * 256 + threadIdx.x;
    if (n < N_NODES) {
        int s = index[n];
        int pos = atomicAdd(&counts[s], 1);
        lists[s * N_NODES + pos] = n;
    }
}

// ---------------------------------------------------------------------------
// Kernel 2: presymmetrize U3 over its (b,j) slots. c,s-independent.
// Output layout: Up[((a*45 + t)*R + il)*M + k]  (k contiguous for the dot)
// ---------------------------------------------------------------------------
template <int M, int R>
__device__ __forceinline__ void presym_elem(const float* __restrict__ u,
                                            float* __restrict__ up, int e) {
    int k  = e % M;
    int r1 = e / M;
    int il = r1 % R;
    int r2 = r1 / R;
    int t  = r2 % NTRI;
    int a  = r2 / NTRI;
    int b = 0, j = 0, acc = 0;
    for (int bb = 0; bb < 9; ++bb) {
        int len = 9 - bb;
        if (t < acc + len) { b = bb; j = bb + (t - acc); break; }
        acc += len;
    }
    float v = u[(((a * 9 + b) * 9 + j) * M + k) * R + il];
    if (j != b) v += u[(((a * 9 + j) * 9 + b) * M + k) * R + il];
    up[e] = v;
}

__global__ __launch_bounds__(256) void presym_kernel(const float* __restrict__ u0,
                                                     const float* __restrict__ u1,
                                                     const float* __restrict__ u2,
                                                     float* __restrict__ ws) {
    int g = blockIdx.x * 256 + threadIdx.x;
    if (g < 4050)               presym_elem<10, 1>(u0, ws, g);
    else if (g < 4050 + 13365)  presym_elem<11, 3>(u1, ws + UPA_SZ, g - 4050);
    else if (g < 43740)         presym_elem<13, 5>(u2, ws + UPA_SZ + UPB_SZ, g - 17415);
}

// ---------------------------------------------------------------------------
struct Params {
    const float* W3[3];
    const float* U2[3]; const float* W2[3];
    const float* U1[3]; const float* W1[3];
};

// dot, u contiguous (presym layout), w stride C_CH (block-uniform -> s_load)
template <int M>
__device__ __forceinline__ float dotk(const float* __restrict__ up, const float* __restrict__ wp) {
    float acc = 0.f;
#pragma unroll
    for (int k = 0; k < M; ++k) acc = __builtin_fmaf(up[k], wp[k * C_CH], acc);
    return acc;
}
// dot, u stride R (original U layout)
template <int M, int R>
__device__ __forceinline__ float dotc(const float* __restrict__ up, const float* __restrict__ wp) {
    float acc = 0.f;
#pragma unroll
    for (int k = 0; k < M; ++k) acc = __builtin_fmaf(up[k * R], wp[k * C_CH], acc);
    return acc;
}

// dynamic index into x[9] without scratch: cndmask chain
__device__ __forceinline__ float selx(const float x[9], int a) {
    float r = x[0];
    r = (a == 1) ? x[1] : r;
    r = (a == 2) ? x[2] : r;
    r = (a == 3) ? x[3] : r;
    r = (a == 4) ? x[4] : r;
    r = (a == 5) ? x[5] : r;
    r = (a == 6) ? x[6] : r;
    r = (a == 7) ? x[7] : r;
    r = (a == 8) ? x[8] : r;
    return r;
}

// ---------------------------------------------------------------------------
// Kernel 3: fused build + eval. 1 wave (64 threads) per (s,c); 4 nodes/thread.
// f32 coefficient rows in LDS (R1's proven no-spill read pattern: float4 pairs
// + scalar i8 plane). a-loop rolled; (b,j) triangle unrolled compile-time.
// sched fences cap load-hoisting to one b-group (<=9 rows) so the scheduler
// cannot recreate the R5 spill blow-up.
// ---------------------------------------------------------------------------
__global__ __launch_bounds__(64, 1) void eval_kernel(const float* __restrict__ nf,
                                                     const int* __restrict__ counts,
                                                     const int* __restrict__ lists,
                                                     const float* __restrict__ Up,
                                                     Params p,
                                                     float* __restrict__ out) {
    __shared__ __align__(16) float sC3[NROW3 * 8];  // [row][i0..7]
    __shared__ float sC3b[NROW3];                   // [row] i==8
    __shared__ __align__(16) float sC2[81 * 8];
    __shared__ float sC2b[81];
    __shared__ __align__(16) float sC1[9 * 8];
    __shared__ float sC1b[9];
    // LDS ~17.9 KB -> 8 blocks/CU cap (grid gives 5)

    const int s = blockIdx.x % N_SPEC;
    const int c = blockIdx.x / N_SPEC;
    const int tid = threadIdx.x;

    // ---- build C3 (405 rows, f32) from presymmetrized Up ----
    {
        const float* UA = Up;
        const float* UB = Up + UPA_SZ;
        const float* UC = Up + UPA_SZ + UPB_SZ;
        const float* w30 = p.W3[0] + (s * 10) * C_CH + c;
        const float* w31 = p.W3[1] + (s * 11) * C_CH + c;
        const float* w32 = p.W3[2] + (s * 13) * C_CH + c;
        for (int e = tid; e < NROW3 * 9; e += 64) {
            int r = e / 9, i = e - r * 9;
            float v;
            if (i == 0)     v = dotk<10>(UA + r * 10, w30);
            else if (i < 4) v = dotk<11>(UB + (r * 3 + (i - 1)) * 11, w31);
            else            v = dotk<13>(UC + (r * 5 + (i - 4)) * 13, w32);
            if (i < 8) sC3[r * 8 + i] = v; else sC3b[r] = v;
        }
    }
    // ---- build C2 (81 rows, f32) ----
    for (int e = tid; e < 729; e += 64) {
        int ab = e / 9, i = e - ab * 9;
        float v;
        if (i == 0)     v = dotc<3, 1>(p.U2[0] + ab * 3,            p.W2[0] + (s * 3) * C_CH + c);
        else if (i < 4) v = dotc<2, 3>(p.U2[1] + ab * 6 + (i - 1),  p.W2[1] + (s * 2) * C_CH + c);
        else            v = dotc<3, 5>(p.U2[2] + ab * 15 + (i - 4), p.W2[2] + (s * 3) * C_CH + c);
        if (i < 8) sC2[ab * 8 + i] = v; else sC2b[ab] = v;
    }
    // ---- build C1 (9 rows, f32) ----
    for (int e = tid; e < 81; e += 64) {
        int a = e / 9, i = e - a * 9;
        float v;
        if (i == 0)     v = p.U1[0][a]               * p.W1[0][s * C_CH + c];
        else if (i < 4) v = p.U1[1][a * 3 + (i - 1)] * p.W1[1][s * C_CH + c];
        else            v = p.U1[2][a * 5 + (i - 4)] * p.W1[2][s * C_CH + c];
        if (i < 8) sC1[a * 8 + i] = v; else sC1b[a] = v;
    }
    __syncthreads();

    const int cnt = counts[s];
    const float4* C3v = (const float4*)sC3;
    const float4* C2v = (const float4*)sC2;
    const float4* C1v = (const float4*)sC1;

    for (int base = 0; base < cnt; base += 256) {
        int nn[4];
        float x[4][9];
#pragma unroll
        for (int pn = 0; pn < 4; ++pn) {
            int idx = base + pn * 64 + tid;
            nn[pn] = (idx < cnt) ? lists[s * N_NODES + idx] : -1;
            const float* xp = nf + ((long)(nn[pn] < 0 ? 0 : nn[pn]) * C_CH + c) * 9;
#pragma unroll
            for (int j = 0; j < 9; ++j) x[pn][j] = xp[j];
        }

        float o[4][9];
#pragma unroll
        for (int pn = 0; pn < 4; ++pn)
#pragma unroll
            for (int i = 0; i < 9; ++i) o[pn][i] = 0.f;

#pragma unroll 1
        for (int a = 0; a < 9; ++a) {
            float xa[4];
#pragma unroll
            for (int pn = 0; pn < 4; ++pn) xa[pn] = selx(x[pn], a);

            // ta init from C1 row a
            float ta[4][9];
            {
                float4 lo = C1v[a * 2], hi = C1v[a * 2 + 1];
                float c1[9] = {lo.x, lo.y, lo.z, lo.w, hi.x, hi.y, hi.z, hi.w, sC1b[a]};
#pragma unroll
                for (int pn = 0; pn < 4; ++pn)
#pragma unroll
                    for (int i = 0; i < 9; ++i) ta[pn][i] = c1[i];
            }

            // quadratic: 9 rows, b compile-time
#pragma unroll
            for (int b = 0; b < 9; ++b) {
                const int ab = a * 9 + b;
                float4 lo = C2v[ab * 2], hi = C2v[ab * 2 + 1];
                float cc[9] = {lo.x, lo.y, lo.z, lo.w, hi.x, hi.y, hi.z, hi.w, sC2b[ab]};
#pragma unroll
                for (int pn = 0; pn < 4; ++pn)
#pragma unroll
                    for (int i = 0; i < 9; ++i)
                        ta[pn][i] = __builtin_fmaf(cc[i], x[pn][b], ta[pn][i]);
            }
            SCHED_FENCE();

            // cubic: symmetrized (b<=j) triangle, 45 rows, compile-time b,j
#pragma unroll
            for (int b = 0; b < 9; ++b) {
#pragma unroll
                for (int j = b; j < 9; ++j) {
                    const int r = a * NTRI + t2idx(b, j);
                    float4 lo = C3v[r * 2], hi = C3v[r * 2 + 1];
                    float cc[9] = {lo.x, lo.y, lo.z, lo.w, hi.x, hi.y, hi.z, hi.w, sC3b[r]};
#pragma unroll
                    for (int pn = 0; pn < 4; ++pn) {
                        const float m = x[pn][b] * x[pn][j];
#pragma unroll
                        for (int i = 0; i < 9; ++i)
                            ta[pn][i] = __builtin_fmaf(cc[i], m, ta[pn][i]);
                    }
                }
                SCHED_FENCE();   // cap hoisting at one b-group (<=9 rows)
            }

#pragma unroll
            for (int pn = 0; pn < 4; ++pn)
#pragma unroll
                for (int i = 0; i < 9; ++i)
                    o[pn][i] = __builtin_fmaf(ta[pn][i], xa[pn], o[pn][i]);
        }

#pragma unroll
        for (int pn = 0; pn < 4; ++pn) {
            if (nn[pn] >= 0) {
                float* op = out + ((long)nn[pn] * C_CH + c) * 9;
#pragma unroll
                for (int i = 0; i < 9; ++i) op[i] = o[pn][i];
            }
        }
    }
}

// ---------------------------------------------------------------------------
extern "C" void kernel_launch(void* const* d_in, const int* in_sizes, int n_in,
                              void* d_out, int out_size, void* d_ws, size_t ws_size,
                              hipStream_t stream) {
    const float* nf  = (const float*)d_in[0];
    const int* index = (const int*)d_in[1];

    Params p;
    p.W3[0] = (const float*)d_in[3];
    p.W3[1] = (const float*)d_in[5];
    p.W3[2] = (const float*)d_in[7];
    p.U2[0] = (const float*)d_in[8];  p.W2[0] = (const float*)d_in[9];
    p.U2[1] = (const float*)d_in[10]; p.W2[1] = (const float*)d_in[11];
    p.U2[2] = (const float*)d_in[12]; p.W2[2] = (const float*)d_in[13];
    p.U1[0] = (const float*)d_in[14]; p.W1[0] = (const float*)d_in[15];
    p.U1[1] = (const float*)d_in[16]; p.W1[1] = (const float*)d_in[17];
    p.U1[2] = (const float*)d_in[18]; p.W1[2] = (const float*)d_in[19];

    int* counts = (int*)d_ws;
    int* lists  = (int*)d_ws + 16;
    float* Up   = (float*)d_ws + WS_UP_OFF;

    hipMemsetAsync(counts, 0, 16 * sizeof(int), stream);
    bucket_kernel<<<(N_NODES + 255) / 256, 256, 0, stream>>>(index, counts, lists);
    presym_kernel<<<(43740 + 255) / 256, 256, 0, stream>>>(
        (const float*)d_in[2], (const float*)d_in[4], (const float*)d_in[6], Up);
    eval_kernel<<<N_SPEC * C_CH, 64, 0, stream>>>(nf, counts, lists, Up, p, (float*)d_out);
}